// Round 1
// baseline (1224.755 us; speedup 1.0000x reference)
//
#include <hip/hip_runtime.h>
#include <hip/hip_bf16.h>
#include <math.h>

#define S_SEQ 4096
#define NDIN  1024
#define NDKQ  1024
#define NDV   1024

__device__ __forceinline__ float waveMax(float v) {
#pragma unroll
    for (int o = 32; o > 0; o >>= 1) v = fmaxf(v, __shfl_down(v, o, 64));
    return v;
}
__device__ __forceinline__ float waveSum(float v) {
#pragma unroll
    for (int o = 32; o > 0; o >>= 1) v += __shfl_down(v, o, 64);
    return v;
}

// C[M,N] = scale * A[M,Kdim] @ op(B).
//   TRANSB=false: B is [Kdim,N] row-major (ldb=N)
//   TRANSB=true : B is [N,Kdim] row-major (ldb=Kdim), C = A @ B^T
//   CAUSAL_SKIP : skip blocks entirely above the diagonal (j > i for all elems)
//   KLIMIT      : k-loop runs only to (bm+1)*64 (causal PV)
// All dims assumed multiples of 64; lda == Kdim for every use in this file.
template<bool TRANSB, bool CAUSAL_SKIP, bool KLIMIT>
__global__ __launch_bounds__(256)
void gemm64x64(const float* __restrict__ A, const float* __restrict__ B,
               float* __restrict__ C, int M, int N, int Kdim, float scale)
{
    const int bn = blockIdx.x, bm = blockIdx.y;
    const int m0 = bm << 6, n0 = bn << 6;
    if (CAUSAL_SKIP && n0 > m0 + 63) return;

    int kend = Kdim;
    if (KLIMIT) { int lim = (bm + 1) << 6; kend = lim < Kdim ? lim : Kdim; }

    __shared__ float As[16][64];
    __shared__ float Bs[16][64];

    const int tid = threadIdx.x;
    const int tx = tid & 15, ty = tid >> 4;

    // A-tile loader: row a_m (0..63), 4 k's starting at a_k
    const int a_m = tid >> 2, a_k = (tid & 3) << 2;
    // B-tile loader (NN): row b_k (0..15), 4 n's starting at b_n
    const int b_k = tid >> 4, b_n = (tid & 15) << 2;

    float acc[4][4] = {};

    for (int k0 = 0; k0 < kend; k0 += 16) {
        const float4 av = *(const float4*)(A + (size_t)(m0 + a_m) * Kdim + k0 + a_k);
        float4 bv;
        if (TRANSB) {
            bv = *(const float4*)(B + (size_t)(n0 + a_m) * Kdim + k0 + a_k);
        } else {
            bv = *(const float4*)(B + (size_t)(k0 + b_k) * N + n0 + b_n);
        }

        __syncthreads();   // previous iteration's compute done before LDS overwrite
        As[a_k + 0][a_m] = av.x;
        As[a_k + 1][a_m] = av.y;
        As[a_k + 2][a_m] = av.z;
        As[a_k + 3][a_m] = av.w;
        if (TRANSB) {
            Bs[a_k + 0][a_m] = bv.x;
            Bs[a_k + 1][a_m] = bv.y;
            Bs[a_k + 2][a_m] = bv.z;
            Bs[a_k + 3][a_m] = bv.w;
        } else {
            *(float4*)&Bs[b_k][b_n] = bv;
        }
        __syncthreads();

#pragma unroll
        for (int k = 0; k < 16; ++k) {
            const float4 a = *(const float4*)&As[k][ty << 2];
            const float4 b = *(const float4*)&Bs[k][tx << 2];
            acc[0][0] += a.x * b.x; acc[0][1] += a.x * b.y; acc[0][2] += a.x * b.z; acc[0][3] += a.x * b.w;
            acc[1][0] += a.y * b.x; acc[1][1] += a.y * b.y; acc[1][2] += a.y * b.z; acc[1][3] += a.y * b.w;
            acc[2][0] += a.z * b.x; acc[2][1] += a.z * b.y; acc[2][2] += a.z * b.z; acc[2][3] += a.z * b.w;
            acc[3][0] += a.w * b.x; acc[3][1] += a.w * b.y; acc[3][2] += a.w * b.z; acc[3][3] += a.w * b.w;
        }
    }

#pragma unroll
    for (int i = 0; i < 4; ++i) {
        float4 o = make_float4(acc[i][0] * scale, acc[i][1] * scale,
                               acc[i][2] * scale, acc[i][3] * scale);
        *(float4*)(C + (size_t)(m0 + (ty << 2) + i) * N + n0 + (tx << 2)) = o;
    }
}

// Row-wise causal softmax over A[i, 0..i] (already scaled by 1/sqrt(d)).
// Also zero-fills j in (i, rowBlockEnd) so PV can read full 64-wide k-tiles.
__global__ __launch_bounds__(256)
void softmax_causal(float* __restrict__ A)
{
    const int i = blockIdx.x;
    float* row = A + (size_t)i * S_SEQ;
    const int n = i + 1;
    const int tid = threadIdx.x;
    __shared__ float red[4];

    float m = -INFINITY;
    for (int j = tid; j < n; j += 256) m = fmaxf(m, row[j]);
    m = waveMax(m);
    if ((tid & 63) == 0) red[tid >> 6] = m;
    __syncthreads();
    const float mAll = fmaxf(fmaxf(red[0], red[1]), fmaxf(red[2], red[3]));

    float s = 0.f;
    for (int j = tid; j < n; j += 256) {
        const float e = __expf(row[j] - mAll);
        row[j] = e;
        s += e;
    }
    s = waveSum(s);
    __syncthreads();                 // everyone done reading red[] as maxes
    if ((tid & 63) == 0) red[tid >> 6] = s;
    __syncthreads();
    const float inv = 1.0f / (red[0] + red[1] + red[2] + red[3]);

    for (int j = tid; j < n; j += 256) row[j] *= inv;

    const int kmax = ((i >> 6) + 1) << 6;      // PV reads k < kmax for this row's tile
    for (int j = n + tid; j < kmax; j += 256) row[j] = 0.f;
}

extern "C" void kernel_launch(void* const* d_in, const int* in_sizes, int n_in,
                              void* d_out, int out_size, void* d_ws, size_t ws_size,
                              hipStream_t stream)
{
    const float* x  = (const float*)d_in[0];
    const float* Wq = (const float*)d_in[1];
    const float* Wk = (const float*)d_in[2];
    const float* Wv = (const float*)d_in[3];
    float* out = (float*)d_out;

    float* Q  = (float*)d_ws;                       // 4096x1024
    float* K  = Q + (size_t)S_SEQ * NDKQ;           // 4096x1024
    float* V  = K + (size_t)S_SEQ * NDKQ;           // 4096x1024
    float* At = V + (size_t)S_SEQ * NDV;            // 4096x4096

    const float scale = 0.03125f;                   // 1/sqrt(1024)

    dim3 blk(256);
    dim3 gProj(NDKQ / 64, S_SEQ / 64);              // 16 x 64
    gemm64x64<false, false, false><<<gProj, blk, 0, stream>>>(x, Wq, Q, S_SEQ, NDKQ, NDIN, 1.0f);
    gemm64x64<false, false, false><<<gProj, blk, 0, stream>>>(x, Wk, K, S_SEQ, NDKQ, NDIN, 1.0f);
    gemm64x64<false, false, false><<<gProj, blk, 0, stream>>>(x, Wv, V, S_SEQ, NDV,  NDIN, 1.0f);

    dim3 gAttn(S_SEQ / 64, S_SEQ / 64);             // 64 x 64, upper blocks early-out
    gemm64x64<true, true, false><<<gAttn, blk, 0, stream>>>(Q, K, At, S_SEQ, S_SEQ, NDKQ, scale);

    softmax_causal<<<dim3(S_SEQ), blk, 0, stream>>>(At);

    dim3 gPV(NDV / 64, S_SEQ / 64);                 // 16 x 64, k-limited per row tile
    gemm64x64<false, false, true><<<gPV, blk, 0, stream>>>(At, V, out, S_SEQ, NDV, S_SEQ, 1.0f);
}

// Round 2
// 409.215 us; speedup vs baseline: 2.9929x; 2.9929x over previous
//
#include <hip/hip_runtime.h>
#include <math.h>

#define SQ 4096
#define DD 1024

typedef _Float16 f16;
typedef f16 f16x8 __attribute__((ext_vector_type(8)));
typedef f16 f16x4 __attribute__((ext_vector_type(4)));
typedef float f32x4 __attribute__((ext_vector_type(4)));

__device__ __forceinline__ float waveMax(float v) {
#pragma unroll
    for (int o = 32; o > 0; o >>= 1) v = fmaxf(v, __shfl_down(v, o, 64));
    return v;
}
__device__ __forceinline__ float waveSum(float v) {
#pragma unroll
    for (int o = 32; o > 0; o >>= 1) v += __shfl_down(v, o, 64);
    return v;
}

__device__ __forceinline__ void gl_lds16(const f16* g, f16* l) {
    __builtin_amdgcn_global_load_lds(
        (const __attribute__((address_space(1))) void*)g,
        (__attribute__((address_space(3))) void*)l, 16, 0, 0);
}

// Stage rows [w*32, w*32+32) of a 128x32 f16 tile (src row-major, ld=ldk) into
// LDS tile laid out [128][32]. LDS dest is wave-uniform base + lane*16B, which
// exactly matches row-major [row][32] coverage: lane L -> row L/4, bytes (L%4)*16.
__device__ __forceinline__ void stage_tile(const f16* src, int ldk, f16* lds, int w, int lane) {
    const f16* g = src + (size_t)((w << 5) + (lane >> 2)) * ldk + ((lane & 3) << 3);
    f16* l = lds + ((w << 5) << 5);
    gl_lds16(g, l);
    gl_lds16(g + ((size_t)ldk << 4), l + (16 << 5));
}

// TN GEMM: C[M,N] = scale * A[M,K] @ B[N,K]^T, both operands K-contiguous f16.
// NSPLIT=3: A=(Ah+Al), B=(Bh+Bl), computes Ah*Bh + Ah*Bl + Al*Bh (fp32-ish).
// NSPLIT=1: plain f16 Ah*Bh.
// STMODE: 0 = f32 row-major C (ld=N); 1 = split-f16 pair (Ch,Cl) row-major;
//         2 = f16 transposed C (Ch is [N][M], ld=M).
// CAUSAL: skip 128x128 tiles strictly above diagonal. KLIMIT: k < (bm+1)*128.
template<int NSPLIT, int STMODE, bool CAUSAL, bool KLIMIT>
__global__ __launch_bounds__(256)
void gemm_tn(const f16* __restrict__ Ah, const f16* __restrict__ Al,
             const f16* __restrict__ Bh, const f16* __restrict__ Bl,
             float* __restrict__ Cf, f16* __restrict__ Ch, f16* __restrict__ Cl,
             int M, int N, int K, float scale)
{
    const int bn = blockIdx.x, bm = blockIdx.y;
    if (CAUSAL && bn > bm) return;
    const int m0 = bm << 7, n0 = bn << 7;
    int kend = K;
    if (KLIMIT) { int lim = (bm + 1) << 7; kend = lim < K ? lim : K; }

    constexpr int NT = (NSPLIT > 1) ? 4 : 2;
    __shared__ f16 sm[NT * 128 * 32];

    const int tid = threadIdx.x;
    const int w = tid >> 6, lane = tid & 63;
    const int wr = (w >> 1) << 6, wc = (w & 1) << 6;   // wave's 64x64 quadrant
    const int fcol = lane & 15, quad = lane >> 4;

    f32x4 acc[4][4];
#pragma unroll
    for (int i = 0; i < 4; ++i)
#pragma unroll
        for (int j = 0; j < 4; ++j) acc[i][j] = (f32x4){0.f, 0.f, 0.f, 0.f};

    const f16* Abase = Ah + (size_t)m0 * K;
    const f16* Bbase = Bh + (size_t)n0 * K;
    const f16* AbaseL = (NSPLIT > 1) ? Al + (size_t)m0 * K : nullptr;
    const f16* BbaseL = (NSPLIT > 1) ? Bl + (size_t)n0 * K : nullptr;

    for (int k0 = 0; k0 < kend; k0 += 32) {
        __syncthreads();                      // prev iter's ds_reads done
        stage_tile(Abase + k0, K, sm + 0 * 4096, w, lane);
        stage_tile(Bbase + k0, K, sm + 1 * 4096, w, lane);
        if (NSPLIT > 1) {
            stage_tile(AbaseL + k0, K, sm + 2 * 4096, w, lane);
            stage_tile(BbaseL + k0, K, sm + 3 * 4096, w, lane);
        }
        __syncthreads();                      // vmcnt drained -> LDS valid

        f16x8 bh[4], blv[4];
#pragma unroll
        for (int in = 0; in < 4; ++in) {
            const int off = ((wc + (in << 4) + fcol) << 5) + (quad << 3);
            bh[in] = *(const f16x8*)&sm[1 * 4096 + off];
            if (NSPLIT > 1) blv[in] = *(const f16x8*)&sm[3 * 4096 + off];
        }
#pragma unroll
        for (int im = 0; im < 4; ++im) {
            const int off = ((wr + (im << 4) + fcol) << 5) + (quad << 3);
            f16x8 ah = *(const f16x8*)&sm[0 * 4096 + off];
            f16x8 alv;
            if (NSPLIT > 1) alv = *(const f16x8*)&sm[2 * 4096 + off];
#pragma unroll
            for (int in = 0; in < 4; ++in) {
                if (NSPLIT > 1) {
                    acc[im][in] = __builtin_amdgcn_mfma_f32_16x16x32_f16(ah, blv[in], acc[im][in], 0, 0, 0);
                    acc[im][in] = __builtin_amdgcn_mfma_f32_16x16x32_f16(alv, bh[in], acc[im][in], 0, 0, 0);
                }
                acc[im][in] = __builtin_amdgcn_mfma_f32_16x16x32_f16(ah, bh[in], acc[im][in], 0, 0, 0);
            }
        }
    }

    // C/D layout: col = lane&15, row = quad*4 + r  [m89-verified]
#pragma unroll
    for (int im = 0; im < 4; ++im) {
#pragma unroll
        for (int in = 0; in < 4; ++in) {
            if (STMODE == 2) {
                const int tr = n0 + wc + (in << 4) + fcol;
                const int tc = m0 + wr + (im << 4) + (quad << 2);
                f16x4 o;
#pragma unroll
                for (int r = 0; r < 4; ++r) o[r] = (f16)(acc[im][in][r] * scale);
                *(f16x4*)&Ch[(size_t)tr * M + tc] = o;
            } else {
#pragma unroll
                for (int r = 0; r < 4; ++r) {
                    const int row = m0 + wr + (im << 4) + (quad << 2) + r;
                    const int col = n0 + wc + (in << 4) + fcol;
                    const float v = acc[im][in][r] * scale;
                    if (STMODE == 0) {
                        Cf[(size_t)row * N + col] = v;
                    } else {
                        const f16 h = (f16)v;
                        Ch[(size_t)row * N + col] = h;
                        Cl[(size_t)row * N + col] = (f16)(v - (float)h);
                    }
                }
            }
        }
    }
}

// x (fp32) -> hi/lo f16 split, elementwise
__global__ __launch_bounds__(256)
void split_f32(const float* __restrict__ x, f16* __restrict__ h, f16* __restrict__ l, int n)
{
    const int i = (blockIdx.x * 256 + threadIdx.x) * 4;
    if (i >= n) return;
    const float4 v = *(const float4*)(x + i);
    const f16 h0 = (f16)v.x, h1 = (f16)v.y, h2 = (f16)v.z, h3 = (f16)v.w;
    f16x4 hv = {h0, h1, h2, h3};
    f16x4 lv = {(f16)(v.x - (float)h0), (f16)(v.y - (float)h1),
                (f16)(v.z - (float)h2), (f16)(v.w - (float)h3)};
    *(f16x4*)(h + i) = hv;
    *(f16x4*)(l + i) = lv;
}

// W [K,N] f32 row-major -> Th,Tl [N,K] f16 (transposed hi/lo split)
__global__ __launch_bounds__(256)
void transpose_split(const float* __restrict__ W, f16* __restrict__ Th, f16* __restrict__ Tl,
                     int K, int N)
{
    __shared__ float t[64][65];
    const int n0 = blockIdx.x << 6, k0 = blockIdx.y << 6;
    const int tx = threadIdx.x & 63, ty = threadIdx.x >> 6;
    for (int r = ty; r < 64; r += 4) t[r][tx] = W[(size_t)(k0 + r) * N + n0 + tx];
    __syncthreads();
    for (int r = ty; r < 64; r += 4) {
        const float v = t[tx][r];
        const f16 h = (f16)v;
        Th[(size_t)(n0 + r) * K + k0 + tx] = h;
        Tl[(size_t)(n0 + r) * K + k0 + tx] = (f16)(v - (float)h);
    }
}

// Row-wise causal softmax: reads f32 logits, writes f16 P, zero-fills to the
// row's 128-tile boundary so the PV GEMM can stage full tiles.
__global__ __launch_bounds__(256)
void softmax_causal(const float* __restrict__ A, f16* __restrict__ P)
{
    const int i = blockIdx.x;
    const float* row = A + (size_t)i * SQ;
    f16* prow = P + (size_t)i * SQ;
    const int n = i + 1;
    const int tid = threadIdx.x, w = tid >> 6, lane = tid & 63;
    __shared__ float redM[4], redS[4];

    float m = -INFINITY;
    for (int j = tid; j < n; j += 256) m = fmaxf(m, row[j]);
    m = waveMax(m);
    if (lane == 0) redM[w] = m;
    __syncthreads();
    const float mAll = fmaxf(fmaxf(redM[0], redM[1]), fmaxf(redM[2], redM[3]));

    float s = 0.f;
    for (int j = tid; j < n; j += 256) {
        const float e = __expf(row[j] - mAll);
        prow[j] = (f16)e;                       // e in [0,1], safe in f16
        s += e;
    }
    s = waveSum(s);
    if (lane == 0) redS[w] = s;
    __syncthreads();
    const float inv = 1.0f / (redS[0] + redS[1] + redS[2] + redS[3]);

    for (int j = tid; j < n; j += 256) prow[j] = (f16)((float)prow[j] * inv);

    const int kmax = ((i >> 7) + 1) << 7;
    for (int j = n + tid; j < kmax; j += 256) prow[j] = (f16)0.f;
}

extern "C" void kernel_launch(void* const* d_in, const int* in_sizes, int n_in,
                              void* d_out, int out_size, void* d_ws, size_t ws_size,
                              hipStream_t stream)
{
    const float* x  = (const float*)d_in[0];
    const float* Wq = (const float*)d_in[1];
    const float* Wk = (const float*)d_in[2];
    const float* Wv = (const float*)d_in[3];
    float* out = (float*)d_out;

    // workspace carve (~172 MB)
    char* p = (char*)d_ws;
    auto take = [&](size_t bytes) { void* r = (void*)p; p += (bytes + 255) & ~(size_t)255; return r; };
    const size_t SD = (size_t)SQ * DD;          // 4M elems
    f16* xh   = (f16*)take(SD * 2);
    f16* xl   = (f16*)take(SD * 2);
    f16* Wqth = (f16*)take((size_t)DD * DD * 2);
    f16* Wqtl = (f16*)take((size_t)DD * DD * 2);
    f16* Wkth = (f16*)take((size_t)DD * DD * 2);
    f16* Wktl = (f16*)take((size_t)DD * DD * 2);
    f16* Wvth = (f16*)take((size_t)DD * DD * 2);
    f16* Wvtl = (f16*)take((size_t)DD * DD * 2);
    f16* Qh   = (f16*)take(SD * 2);
    f16* Ql   = (f16*)take(SD * 2);
    f16* Kh   = (f16*)take(SD * 2);
    f16* Kl   = (f16*)take(SD * 2);
    f16* Vt   = (f16*)take(SD * 2);             // [DD][SQ]
    float* attn = (float*)take((size_t)SQ * SQ * 4);
    f16* P    = (f16*)take((size_t)SQ * SQ * 2);

    const dim3 blk(256);

    split_f32<<<dim3(SD / 4 / 256), blk, 0, stream>>>(x, xh, xl, (int)SD);
    const dim3 gT(DD / 64, DD / 64);
    transpose_split<<<gT, blk, 0, stream>>>(Wq, Wqth, Wqtl, DD, DD);
    transpose_split<<<gT, blk, 0, stream>>>(Wk, Wkth, Wktl, DD, DD);
    transpose_split<<<gT, blk, 0, stream>>>(Wv, Wvth, Wvtl, DD, DD);

    const dim3 gProj(DD / 128, SQ / 128);       // 8 x 32
    // Q = x @ Wq (split3, split-store)
    gemm_tn<3, 1, false, false><<<gProj, blk, 0, stream>>>(
        xh, xl, Wqth, Wqtl, nullptr, Qh, Ql, SQ, DD, DD, 1.0f);
    // K = x @ Wk
    gemm_tn<3, 1, false, false><<<gProj, blk, 0, stream>>>(
        xh, xl, Wkth, Wktl, nullptr, Kh, Kl, SQ, DD, DD, 1.0f);
    // V^T = (x @ Wv)^T, plain f16, transposed f16 store
    gemm_tn<1, 2, false, false><<<gProj, blk, 0, stream>>>(
        xh, nullptr, Wvth, nullptr, nullptr, Vt, nullptr, SQ, DD, DD, 1.0f);

    // attn = Q @ K^T / 32  (split3, causal tile skip, f32 store)
    const dim3 gAttn(SQ / 128, SQ / 128);       // 32 x 32
    gemm_tn<3, 0, true, false><<<gAttn, blk, 0, stream>>>(
        Qh, Ql, Kh, Kl, attn, nullptr, nullptr, SQ, SQ, DD, 0.03125f);

    softmax_causal<<<dim3(SQ), blk, 0, stream>>>(attn, P);

    // out = P @ V  (A=P [SQ,SQ], B=Vt [DD,SQ], plain f16, k-limited)
    const dim3 gPV(DD / 128, SQ / 128);         // 8 x 32
    gemm_tn<1, 0, false, true><<<gPV, blk, 0, stream>>>(
        P, nullptr, Vt, nullptr, out, nullptr, nullptr, SQ, DD, SQ, 1.0f);
}

// Round 3
// 400.726 us; speedup vs baseline: 3.0563x; 1.0212x over previous
//
#include <hip/hip_runtime.h>
#include <math.h>

#define SQ 4096
#define DD 1024

typedef _Float16 f16;
typedef f16 f16x8 __attribute__((ext_vector_type(8)));
typedef f16 f16x4 __attribute__((ext_vector_type(4)));
typedef float f32x4 __attribute__((ext_vector_type(4)));

__device__ __forceinline__ float waveMax(float v) {
#pragma unroll
    for (int o = 32; o > 0; o >>= 1) v = fmaxf(v, __shfl_down(v, o, 64));
    return v;
}
__device__ __forceinline__ float waveSum(float v) {
#pragma unroll
    for (int o = 32; o > 0; o >>= 1) v += __shfl_down(v, o, 64);
    return v;
}

__device__ __forceinline__ void gl_lds16(const f16* g, f16* l) {
    __builtin_amdgcn_global_load_lds(
        (const __attribute__((address_space(1))) void*)g,
        (__attribute__((address_space(3))) void*)l, 16, 0, 0);
}

// LDS tile: logical [128 rows][32 k] f16, physical row = 64 B = 4 chunks of 16 B.
// XOR swizzle: physical_chunk = logical_chunk ^ ((row>>2)&3). This makes every
// 16-lane same-chunk fragment read hit bank-starts {0,4,..,28} exactly twice
// (2-way = free, m136) instead of 8-way on 2 bank groups.
//
// Staging: gl_lds dest is fixed at lane*16B -> lane L owns (row=L>>2, pc=L&3);
// we permute the GLOBAL source chunk so that pc holds lc = pc ^ ((row>>2)&3).
// Same 64B segments are fetched per 4-lane group, so VMEM coalescing unchanged.
__device__ __forceinline__ void stage_tile(const f16* src, int ldk, f16* lds, int w, int lane) {
    const int lc = (lane & 3) ^ ((lane >> 4) & 3);     // (row>>2)&3 == (lane>>4)&3
    const f16* g = src + (size_t)((w << 5) + (lane >> 2)) * ldk + (lc << 3);
    f16* l = lds + ((w << 5) << 5);
    gl_lds16(g, l);
    gl_lds16(g + ((size_t)ldk << 4), l + (16 << 5));   // rows +16: same swizzle phase
}

__device__ __forceinline__ int swz_off(int row, int kc) {
    return (row << 5) + (((kc ^ (row >> 2)) & 3) << 3);
}

// TN GEMM: C[M,N] = scale * A[M,K] @ B[N,K]^T, both operands K-contiguous f16.
// NSPLIT=3: A=(Ah+Al), B=(Bh+Bl), computes Ah*Bh + Ah*Bl + Al*Bh (fp32-ish).
// NSPLIT=1: plain f16 Ah*Bh.
// STMODE: 0 = f32 row-major C (ld=N); 1 = split-f16 pair (Ch,Cl) row-major;
//         2 = f16 transposed C (Ch is [N][M], ld=M).
// CAUSAL: skip 128x128 tiles strictly above diagonal. KLIMIT: k < (bm+1)*128.
template<int NSPLIT, int STMODE, bool CAUSAL, bool KLIMIT>
__global__ __launch_bounds__(256)
void gemm_tn(const f16* __restrict__ Ah, const f16* __restrict__ Al,
             const f16* __restrict__ Bh, const f16* __restrict__ Bl,
             float* __restrict__ Cf, f16* __restrict__ Ch, f16* __restrict__ Cl,
             int M, int N, int K, float scale)
{
    const int bn = blockIdx.x, bm = blockIdx.y;
    if (CAUSAL && bn > bm) return;
    const int m0 = bm << 7, n0 = bn << 7;
    int kend = K;
    if (KLIMIT) { int lim = (bm + 1) << 7; kend = lim < K ? lim : K; }

    constexpr int NT = (NSPLIT > 1) ? 4 : 2;
    __shared__ f16 sm[NT * 128 * 32];

    const int tid = threadIdx.x;
    const int w = tid >> 6, lane = tid & 63;
    const int wr = (w >> 1) << 6, wc = (w & 1) << 6;   // wave's 64x64 quadrant
    const int fcol = lane & 15, quad = lane >> 4;

    f32x4 acc[4][4];
#pragma unroll
    for (int i = 0; i < 4; ++i)
#pragma unroll
        for (int j = 0; j < 4; ++j) acc[i][j] = (f32x4){0.f, 0.f, 0.f, 0.f};

    const f16* Abase = Ah + (size_t)m0 * K;
    const f16* Bbase = Bh + (size_t)n0 * K;
    const f16* AbaseL = (NSPLIT > 1) ? Al + (size_t)m0 * K : nullptr;
    const f16* BbaseL = (NSPLIT > 1) ? Bl + (size_t)n0 * K : nullptr;

    for (int k0 = 0; k0 < kend; k0 += 32) {
        __syncthreads();                      // prev iter's ds_reads done
        stage_tile(Abase + k0, K, sm + 0 * 4096, w, lane);
        stage_tile(Bbase + k0, K, sm + 1 * 4096, w, lane);
        if (NSPLIT > 1) {
            stage_tile(AbaseL + k0, K, sm + 2 * 4096, w, lane);
            stage_tile(BbaseL + k0, K, sm + 3 * 4096, w, lane);
        }
        __syncthreads();                      // vmcnt drained -> LDS valid

        f16x8 bh[4], blv[4];
#pragma unroll
        for (int in = 0; in < 4; ++in) {
            const int off = swz_off(wc + (in << 4) + fcol, quad);
            bh[in] = *(const f16x8*)&sm[1 * 4096 + off];
            if (NSPLIT > 1) blv[in] = *(const f16x8*)&sm[3 * 4096 + off];
        }
#pragma unroll
        for (int im = 0; im < 4; ++im) {
            const int off = swz_off(wr + (im << 4) + fcol, quad);
            f16x8 ah = *(const f16x8*)&sm[0 * 4096 + off];
            f16x8 alv;
            if (NSPLIT > 1) alv = *(const f16x8*)&sm[2 * 4096 + off];
#pragma unroll
            for (int in = 0; in < 4; ++in) {
                if (NSPLIT > 1) {
                    acc[im][in] = __builtin_amdgcn_mfma_f32_16x16x32_f16(ah, blv[in], acc[im][in], 0, 0, 0);
                    acc[im][in] = __builtin_amdgcn_mfma_f32_16x16x32_f16(alv, bh[in], acc[im][in], 0, 0, 0);
                }
                acc[im][in] = __builtin_amdgcn_mfma_f32_16x16x32_f16(ah, bh[in], acc[im][in], 0, 0, 0);
            }
        }
    }

    // C/D layout: col = lane&15, row = quad*4 + r  [m89-verified]
#pragma unroll
    for (int im = 0; im < 4; ++im) {
#pragma unroll
        for (int in = 0; in < 4; ++in) {
            if (STMODE == 2) {
                const int tr = n0 + wc + (in << 4) + fcol;
                const int tc = m0 + wr + (im << 4) + (quad << 2);
                f16x4 o;
#pragma unroll
                for (int r = 0; r < 4; ++r) o[r] = (f16)(acc[im][in][r] * scale);
                *(f16x4*)&Ch[(size_t)tr * M + tc] = o;
            } else {
#pragma unroll
                for (int r = 0; r < 4; ++r) {
                    const int row = m0 + wr + (im << 4) + (quad << 2) + r;
                    const int col = n0 + wc + (in << 4) + fcol;
                    const float v = acc[im][in][r] * scale;
                    if (STMODE == 0) {
                        Cf[(size_t)row * N + col] = v;
                    } else {
                        const f16 h = (f16)v;
                        Ch[(size_t)row * N + col] = h;
                        Cl[(size_t)row * N + col] = (f16)(v - (float)h);
                    }
                }
            }
        }
    }
}

// x (fp32) -> hi/lo f16 split, elementwise
__global__ __launch_bounds__(256)
void split_f32(const float* __restrict__ x, f16* __restrict__ h, f16* __restrict__ l, int n)
{
    const int i = (blockIdx.x * 256 + threadIdx.x) * 4;
    if (i >= n) return;
    const float4 v = *(const float4*)(x + i);
    const f16 h0 = (f16)v.x, h1 = (f16)v.y, h2 = (f16)v.z, h3 = (f16)v.w;
    f16x4 hv = {h0, h1, h2, h3};
    f16x4 lv = {(f16)(v.x - (float)h0), (f16)(v.y - (float)h1),
                (f16)(v.z - (float)h2), (f16)(v.w - (float)h3)};
    *(f16x4*)(h + i) = hv;
    *(f16x4*)(l + i) = lv;
}

// W [K,N] f32 row-major -> Th,Tl [N,K] f16 (transposed hi/lo split).
// z-batched over the 3 weight matrices.
__global__ __launch_bounds__(256)
void transpose_split3(const float* __restrict__ W0, const float* __restrict__ W1,
                      const float* __restrict__ W2,
                      f16* __restrict__ T0h, f16* __restrict__ T0l,
                      f16* __restrict__ T1h, f16* __restrict__ T1l,
                      f16* __restrict__ T2h, f16* __restrict__ T2l,
                      int K, int N)
{
    const float* W = (blockIdx.z == 0) ? W0 : (blockIdx.z == 1) ? W1 : W2;
    f16* Th = (blockIdx.z == 0) ? T0h : (blockIdx.z == 1) ? T1h : T2h;
    f16* Tl = (blockIdx.z == 0) ? T0l : (blockIdx.z == 1) ? T1l : T2l;

    __shared__ float t[64][65];
    const int n0 = blockIdx.x << 6, k0 = blockIdx.y << 6;
    const int tx = threadIdx.x & 63, ty = threadIdx.x >> 6;
    for (int r = ty; r < 64; r += 4) t[r][tx] = W[(size_t)(k0 + r) * N + n0 + tx];
    __syncthreads();
    for (int r = ty; r < 64; r += 4) {
        const float v = t[tx][r];
        const f16 h = (f16)v;
        Th[(size_t)(n0 + r) * K + k0 + tx] = h;
        Tl[(size_t)(n0 + r) * K + k0 + tx] = (f16)(v - (float)h);
    }
}

// Row-wise causal softmax: reads f32 logits, writes f16 P, zero-fills to the
// row's 128-tile boundary so the PV GEMM can stage full tiles.
__global__ __launch_bounds__(256)
void softmax_causal(const float* __restrict__ A, f16* __restrict__ P)
{
    const int i = blockIdx.x;
    const float* row = A + (size_t)i * SQ;
    f16* prow = P + (size_t)i * SQ;
    const int n = i + 1;
    const int tid = threadIdx.x, w = tid >> 6, lane = tid & 63;
    __shared__ float redM[4], redS[4];

    float m = -INFINITY;
    for (int j = tid; j < n; j += 256) m = fmaxf(m, row[j]);
    m = waveMax(m);
    if (lane == 0) redM[w] = m;
    __syncthreads();
    const float mAll = fmaxf(fmaxf(redM[0], redM[1]), fmaxf(redM[2], redM[3]));

    float s = 0.f;
    for (int j = tid; j < n; j += 256) {
        const float e = __expf(row[j] - mAll);
        prow[j] = (f16)e;                       // e in [0,1], safe in f16
        s += e;
    }
    s = waveSum(s);
    if (lane == 0) redS[w] = s;
    __syncthreads();
    const float inv = 1.0f / (redS[0] + redS[1] + redS[2] + redS[3]);

    for (int j = tid; j < n; j += 256) prow[j] = (f16)((float)prow[j] * inv);

    const int kmax = ((i >> 7) + 1) << 7;
    for (int j = n + tid; j < kmax; j += 256) prow[j] = (f16)0.f;
}

extern "C" void kernel_launch(void* const* d_in, const int* in_sizes, int n_in,
                              void* d_out, int out_size, void* d_ws, size_t ws_size,
                              hipStream_t stream)
{
    const float* x  = (const float*)d_in[0];
    const float* Wq = (const float*)d_in[1];
    const float* Wk = (const float*)d_in[2];
    const float* Wv = (const float*)d_in[3];
    float* out = (float*)d_out;

    // workspace carve (~172 MB)
    char* p = (char*)d_ws;
    auto take = [&](size_t bytes) { void* r = (void*)p; p += (bytes + 255) & ~(size_t)255; return r; };
    const size_t SD = (size_t)SQ * DD;          // 4M elems
    f16* xh   = (f16*)take(SD * 2);
    f16* xl   = (f16*)take(SD * 2);
    f16* Wqth = (f16*)take((size_t)DD * DD * 2);
    f16* Wqtl = (f16*)take((size_t)DD * DD * 2);
    f16* Wkth = (f16*)take((size_t)DD * DD * 2);
    f16* Wktl = (f16*)take((size_t)DD * DD * 2);
    f16* Wvth = (f16*)take((size_t)DD * DD * 2);
    f16* Wvtl = (f16*)take((size_t)DD * DD * 2);
    f16* Qh   = (f16*)take(SD * 2);
    f16* Ql   = (f16*)take(SD * 2);
    f16* Kh   = (f16*)take(SD * 2);
    f16* Kl   = (f16*)take(SD * 2);
    f16* Vt   = (f16*)take(SD * 2);             // [DD][SQ]
    float* attn = (float*)take((size_t)SQ * SQ * 4);
    f16* P    = (f16*)take((size_t)SQ * SQ * 2);

    const dim3 blk(256);

    split_f32<<<dim3(SD / 4 / 256), blk, 0, stream>>>(x, xh, xl, (int)SD);
    transpose_split3<<<dim3(DD / 64, DD / 64, 3), blk, 0, stream>>>(
        Wq, Wk, Wv, Wqth, Wqtl, Wkth, Wktl, Wvth, Wvtl, DD, DD);

    const dim3 gProj(DD / 128, SQ / 128);       // 8 x 32
    // Q = x @ Wq (split3, split-store)
    gemm_tn<3, 1, false, false><<<gProj, blk, 0, stream>>>(
        xh, xl, Wqth, Wqtl, nullptr, Qh, Ql, SQ, DD, DD, 1.0f);
    // K = x @ Wk
    gemm_tn<3, 1, false, false><<<gProj, blk, 0, stream>>>(
        xh, xl, Wkth, Wktl, nullptr, Kh, Kl, SQ, DD, DD, 1.0f);
    // V^T = (x @ Wv)^T, plain f16, transposed f16 store
    gemm_tn<1, 2, false, false><<<gProj, blk, 0, stream>>>(
        xh, nullptr, Wvth, nullptr, nullptr, Vt, nullptr, SQ, DD, DD, 1.0f);

    // attn = Q @ K^T / 32  (split3, causal tile skip, f32 store)
    const dim3 gAttn(SQ / 128, SQ / 128);       // 32 x 32
    gemm_tn<3, 0, true, false><<<gAttn, blk, 0, stream>>>(
        Qh, Ql, Kh, Kl, attn, nullptr, nullptr, SQ, SQ, DD, 0.03125f);

    softmax_causal<<<dim3(SQ), blk, 0, stream>>>(attn, P);

    // out = P @ V  (A=P [SQ,SQ], B=Vt [DD,SQ], plain f16, k-limited)
    const dim3 gPV(DD / 128, SQ / 128);         // 8 x 32
    gemm_tn<1, 0, false, true><<<gPV, blk, 0, stream>>>(
        P, nullptr, Vt, nullptr, out, nullptr, nullptr, SQ, DD, SQ, 1.0f);
}

// Round 4
// 342.650 us; speedup vs baseline: 3.5744x; 1.1695x over previous
//
#include <hip/hip_runtime.h>
#include <math.h>

#define SQ 4096
#define DD 1024

typedef _Float16 f16;
typedef f16 f16x8 __attribute__((ext_vector_type(8)));
typedef f16 f16x4 __attribute__((ext_vector_type(4)));
typedef float f32x4 __attribute__((ext_vector_type(4)));

__device__ __forceinline__ float waveMax(float v) {
#pragma unroll
    for (int o = 32; o > 0; o >>= 1) v = fmaxf(v, __shfl_down(v, o, 64));
    return v;
}
__device__ __forceinline__ float waveSum(float v) {
#pragma unroll
    for (int o = 32; o > 0; o >>= 1) v += __shfl_down(v, o, 64);
    return v;
}

__device__ __forceinline__ void gl_lds16(const f16* g, f16* l) {
    __builtin_amdgcn_global_load_lds(
        (const __attribute__((address_space(1))) void*)g,
        (__attribute__((address_space(3))) void*)l, 16, 0, 0);
}

// Wave w stages NRW rows of a [*,32] f16 tile into LDS laid out row-major [rows][32].
// gl_lds dest = wave-uniform base + lane*16B: lane L -> row w*NRW + L/4, chunk L%4.
template<int NRW>
__device__ __forceinline__ void stage(const f16* src, int ldk, f16* lds, int w, int lane) {
    const int r0 = w * NRW + (lane >> 2);
    const f16* g = src + (size_t)r0 * ldk + ((lane & 3) << 3);
    f16* l = lds + w * NRW * 32;
    gl_lds16(g, l);
    if (NRW == 32) gl_lds16(g + (size_t)ldk * 16, l + 16 * 32);
}

// Unified TN GEMM over K-contiguous f16 operands.
// MODE 0: merged QKV projection. A=x(h,l) [SQ,DD], B=Wqkv^T(h,l) [3072,DD].
//         Tile 128x128, grid (24,32)=768 blocks. bn<16 (Q,K): split3 math +
//         hi/lo f16 split-store. bn>=16 (V): hi-only math + transposed f16 store.
// MODE 1: QK^T. A=Q(h,l), B=K(h,l), split3, tile 64x128, causal block skip,
//         f32 store * scale. grid (32,64), 1056 active blocks.
// MODE 2: PV. A=P f16 [SQ,SQ], B=Vt f16 [DD,SQ], hi-only, tile 64x128,
//         kend=((bm>>1)+1)*128 (P zero-filled to that boundary). grid (8,64).
template<int MODE>
__global__ __launch_bounds__(256)
void gemm_k(const f16* __restrict__ Ah, const f16* __restrict__ Al,
            const f16* __restrict__ Bh, const f16* __restrict__ Bl,
            float* __restrict__ Cf,
            f16* __restrict__ Qh, f16* __restrict__ Ql,
            f16* __restrict__ Kh, f16* __restrict__ Kl,
            f16* __restrict__ Vt, float scale)
{
    constexpr int TM = (MODE == 0) ? 128 : 64;
    constexpr int NI = (MODE == 0) ? 4 : 2;       // 16-col frags per wave
    constexpr int ASZ = TM * 32;                  // f16 elems
    constexpr int BSZ = 128 * 32;

    const int bn = blockIdx.x, bm = blockIdx.y;
    if (MODE == 1 && bn > (bm >> 1)) return;
    const int m0 = bm * TM;
    const int n0 = bn << 7;
    const int lda = (MODE == 2) ? SQ : DD;
    const int ldb = (MODE == 2) ? SQ : DD;
    const int kend = (MODE == 2) ? (((bm >> 1) + 1) << 7) : DD;
    const bool dolo = (MODE == 1) || (MODE == 0 && bn < 16);

    __shared__ f16 sm[(MODE == 2) ? (ASZ + BSZ) : 2 * (ASZ + BSZ)];
    f16* smA = sm;
    f16* smB = sm + ASZ;
    f16* smAl = sm + ASZ + BSZ;          // valid only when split staged
    f16* smBl = sm + 2 * ASZ + BSZ;

    const int tid = threadIdx.x;
    const int w = tid >> 6, lane = tid & 63;
    const int wr = (MODE == 0) ? ((w >> 1) << 6) : 0;            // wave row base
    const int wc = (MODE == 0) ? ((w & 1) << 6) : (w << 5);      // wave col base
    const int fcol = lane & 15, quad = lane >> 4;

    f32x4 acc[4][NI];
#pragma unroll
    for (int i = 0; i < 4; ++i)
#pragma unroll
        for (int j = 0; j < NI; ++j) acc[i][j] = (f32x4){0.f, 0.f, 0.f, 0.f};

    const f16* Ab = Ah + (size_t)m0 * lda;
    const f16* Bb = Bh + (size_t)n0 * ldb;
    const f16* Abl = dolo ? Al + (size_t)m0 * lda : nullptr;
    const f16* Bbl = dolo ? Bl + (size_t)n0 * ldb : nullptr;

    for (int k0 = 0; k0 < kend; k0 += 32) {
        __syncthreads();                          // prev iter's ds_reads done
        stage<TM / 4>(Ab + k0, lda, smA, w, lane);
        stage<32>(Bb + k0, ldb, smB, w, lane);
        if (dolo) {
            stage<TM / 4>(Abl + k0, lda, smAl, w, lane);
            stage<32>(Bbl + k0, ldb, smBl, w, lane);
        }
        __syncthreads();                          // vmcnt drained -> LDS valid

        f16x8 bh[NI], bl[NI];
#pragma unroll
        for (int in = 0; in < NI; ++in) {
            const int off = ((wc + (in << 4) + fcol) << 5) + (quad << 3);
            bh[in] = *(const f16x8*)&smB[off];
            if (dolo) bl[in] = *(const f16x8*)&smBl[off];
        }
#pragma unroll
        for (int im = 0; im < 4; ++im) {
            const int off = ((wr + (im << 4) + fcol) << 5) + (quad << 3);
            f16x8 ah = *(const f16x8*)&smA[off];
            f16x8 al;
            if (dolo) al = *(const f16x8*)&smAl[off];
#pragma unroll
            for (int in = 0; in < NI; ++in) {
                if (dolo) {
                    acc[im][in] = __builtin_amdgcn_mfma_f32_16x16x32_f16(ah, bl[in], acc[im][in], 0, 0, 0);
                    acc[im][in] = __builtin_amdgcn_mfma_f32_16x16x32_f16(al, bh[in], acc[im][in], 0, 0, 0);
                }
                acc[im][in] = __builtin_amdgcn_mfma_f32_16x16x32_f16(ah, bh[in], acc[im][in], 0, 0, 0);
            }
        }
    }

    // C/D layout: col = lane&15, row = quad*4 + r  [m89-verified]
#pragma unroll
    for (int im = 0; im < 4; ++im) {
#pragma unroll
        for (int in = 0; in < NI; ++in) {
            if (MODE == 0) {
                const int region = bn >> 3;                       // 0=Q 1=K 2=V
                const int colL = ((bn & 7) << 7) + wc + (in << 4) + fcol;
                if (region == 2) {
                    const int tc = m0 + wr + (im << 4) + (quad << 2);
                    f16x4 o;
#pragma unroll
                    for (int r = 0; r < 4; ++r) o[r] = (f16)acc[im][in][r];
                    *(f16x4*)&Vt[(size_t)colL * SQ + tc] = o;
                } else {
                    f16* Hh = region ? Kh : Qh;
                    f16* Hl = region ? Kl : Ql;
#pragma unroll
                    for (int r = 0; r < 4; ++r) {
                        const int row = m0 + wr + (im << 4) + (quad << 2) + r;
                        const float v = acc[im][in][r];
                        const f16 h = (f16)v;
                        Hh[(size_t)row * DD + colL] = h;
                        Hl[(size_t)row * DD + colL] = (f16)(v - (float)h);
                    }
                }
            } else {
                const int ldc = (MODE == 1) ? SQ : DD;
#pragma unroll
                for (int r = 0; r < 4; ++r) {
                    const int row = m0 + wr + (im << 4) + (quad << 2) + r;
                    const int col = n0 + wc + (in << 4) + fcol;
                    Cf[(size_t)row * ldc + col] = acc[im][in][r] * scale;
                }
            }
        }
    }
}

// x (fp32) -> hi/lo f16 split, elementwise
__global__ __launch_bounds__(256)
void split_f32(const float* __restrict__ x, f16* __restrict__ h, f16* __restrict__ l, int n)
{
    const int i = (blockIdx.x * 256 + threadIdx.x) * 4;
    if (i >= n) return;
    const float4 v = *(const float4*)(x + i);
    const f16 h0 = (f16)v.x, h1 = (f16)v.y, h2 = (f16)v.z, h3 = (f16)v.w;
    f16x4 hv = {h0, h1, h2, h3};
    f16x4 lv = {(f16)(v.x - (float)h0), (f16)(v.y - (float)h1),
                (f16)(v.z - (float)h2), (f16)(v.w - (float)h3)};
    *(f16x4*)(h + i) = hv;
    *(f16x4*)(l + i) = lv;
}

// W [K,N] f32 row-major -> Th,Tl [N,K] f16 (transposed hi/lo split).
// z-batched over the 3 weight matrices (written into one [3072,1024] buffer).
__global__ __launch_bounds__(256)
void transpose_split3(const float* __restrict__ W0, const float* __restrict__ W1,
                      const float* __restrict__ W2,
                      f16* __restrict__ Th0, f16* __restrict__ Tl0,
                      int K, int N)
{
    const float* W = (blockIdx.z == 0) ? W0 : (blockIdx.z == 1) ? W1 : W2;
    f16* Th = Th0 + (size_t)blockIdx.z * K * N;
    f16* Tl = Tl0 + (size_t)blockIdx.z * K * N;

    __shared__ float t[64][65];
    const int n0 = blockIdx.x << 6, k0 = blockIdx.y << 6;
    const int tx = threadIdx.x & 63, ty = threadIdx.x >> 6;
    for (int r = ty; r < 64; r += 4) t[r][tx] = W[(size_t)(k0 + r) * N + n0 + tx];
    __syncthreads();
    for (int r = ty; r < 64; r += 4) {
        const float v = t[tx][r];
        const f16 h = (f16)v;
        Th[(size_t)(n0 + r) * K + k0 + tx] = h;
        Tl[(size_t)(n0 + r) * K + k0 + tx] = (f16)(v - (float)h);
    }
}

// Row-wise causal softmax: reads f32 logits, writes f16 P, zero-fills to the
// row's 128-tile boundary so the PV GEMM can stage full tiles.
__global__ __launch_bounds__(256)
void softmax_causal(const float* __restrict__ A, f16* __restrict__ P)
{
    const int i = blockIdx.x;
    const float* row = A + (size_t)i * SQ;
    f16* prow = P + (size_t)i * SQ;
    const int n = i + 1;
    const int tid = threadIdx.x, w = tid >> 6, lane = tid & 63;
    __shared__ float redM[4], redS[4];

    float m = -INFINITY;
    for (int j = tid; j < n; j += 256) m = fmaxf(m, row[j]);
    m = waveMax(m);
    if (lane == 0) redM[w] = m;
    __syncthreads();
    const float mAll = fmaxf(fmaxf(redM[0], redM[1]), fmaxf(redM[2], redM[3]));

    float s = 0.f;
    for (int j = tid; j < n; j += 256) {
        const float e = __expf(row[j] - mAll);
        prow[j] = (f16)e;                       // e in [0,1], safe in f16
        s += e;
    }
    s = waveSum(s);
    if (lane == 0) redS[w] = s;
    __syncthreads();
    const float inv = 1.0f / (redS[0] + redS[1] + redS[2] + redS[3]);

    for (int j = tid; j < n; j += 256) prow[j] = (f16)((float)prow[j] * inv);

    const int kmax = ((i >> 7) + 1) << 7;
    for (int j = n + tid; j < kmax; j += 256) prow[j] = (f16)0.f;
}

extern "C" void kernel_launch(void* const* d_in, const int* in_sizes, int n_in,
                              void* d_out, int out_size, void* d_ws, size_t ws_size,
                              hipStream_t stream)
{
    const float* x  = (const float*)d_in[0];
    const float* Wq = (const float*)d_in[1];
    const float* Wk = (const float*)d_in[2];
    const float* Wv = (const float*)d_in[3];
    float* out = (float*)d_out;

    // workspace carve (~164 MB)
    char* p = (char*)d_ws;
    auto take = [&](size_t bytes) { void* r = (void*)p; p += (bytes + 255) & ~(size_t)255; return r; };
    const size_t SD = (size_t)SQ * DD;          // 4M elems
    f16* xh  = (f16*)take(SD * 2);
    f16* xl  = (f16*)take(SD * 2);
    f16* Wth = (f16*)take((size_t)3 * DD * DD * 2);   // [3072][1024] = Wq^T|Wk^T|Wv^T
    f16* Wtl = (f16*)take((size_t)3 * DD * DD * 2);
    f16* Qh  = (f16*)take(SD * 2);
    f16* Ql  = (f16*)take(SD * 2);
    f16* Kh  = (f16*)take(SD * 2);
    f16* Kl  = (f16*)take(SD * 2);
    f16* Vt  = (f16*)take(SD * 2);              // [DD][SQ]
    float* attn = (float*)take((size_t)SQ * SQ * 4);
    f16* P   = (f16*)take((size_t)SQ * SQ * 2);

    const dim3 blk(256);

    split_f32<<<dim3(SD / 4 / 256), blk, 0, stream>>>(x, xh, xl, (int)SD);
    transpose_split3<<<dim3(DD / 64, DD / 64, 3), blk, 0, stream>>>(
        Wq, Wk, Wv, Wth, Wtl, DD, DD);

    // Merged QKV projection: 768 blocks
    gemm_k<0><<<dim3(24, SQ / 128), blk, 0, stream>>>(
        xh, xl, Wth, Wtl, nullptr, Qh, Ql, Kh, Kl, Vt, 1.0f);

    // attn = Q @ K^T / 32 : 64x128 tiles, 1056 causal blocks
    gemm_k<1><<<dim3(SQ / 128, SQ / 64), blk, 0, stream>>>(
        Qh, Ql, Kh, Kl, attn, nullptr, nullptr, nullptr, nullptr, nullptr, 0.03125f);

    softmax_causal<<<dim3(SQ), blk, 0, stream>>>(attn, P);

    // out = P @ V : 64x128 tiles, 512 blocks, k-limited
    gemm_k<2><<<dim3(DD / 128, SQ / 64), blk, 0, stream>>>(
        P, nullptr, Vt, nullptr, out, nullptr, nullptr, nullptr, nullptr, nullptr, 1.0f);
}

// Round 5
// 303.148 us; speedup vs baseline: 4.0401x; 1.1303x over previous
//
#include <hip/hip_runtime.h>
#include <math.h>

#define SQ 4096
#define DD 1024

typedef _Float16 f16;
typedef f16 f16x8 __attribute__((ext_vector_type(8)));
typedef f16 f16x4 __attribute__((ext_vector_type(4)));
typedef float f32x4 __attribute__((ext_vector_type(4)));

__device__ __forceinline__ float waveMax(float v) {
#pragma unroll
    for (int o = 32; o > 0; o >>= 1) v = fmaxf(v, __shfl_down(v, o, 64));
    return v;
}
__device__ __forceinline__ float waveSum(float v) {
#pragma unroll
    for (int o = 32; o > 0; o >>= 1) v += __shfl_down(v, o, 64);
    return v;
}

__device__ __forceinline__ void gl_lds16(const f16* g, f16* l) {
    __builtin_amdgcn_global_load_lds(
        (const __attribute__((address_space(1))) void*)g,
        (__attribute__((address_space(3))) void*)l, 16, 0, 0);
}

// Wave w stages NRW rows of a [*,32] f16 half-tile into LDS row-major [rows][32].
// gl_lds dest = wave-uniform base + lane*16B: lane L -> row w*NRW + L/4, chunk L%4.
// 64 B row stride = proven conflict-free layout; no padding (gl_lds constraint).
template<int NRW>
__device__ __forceinline__ void stage(const f16* src, int ldk, f16* lds, int w, int lane) {
    const int r0 = w * NRW + (lane >> 2);
    const f16* g = src + (size_t)r0 * ldk + ((lane & 3) << 3);
    f16* l = lds + w * NRW * 32;
    gl_lds16(g, l);
    if (NRW == 32) gl_lds16(g + (size_t)ldk * 16, l + 16 * 32);
}

// Unified TN GEMM over K-contiguous f16 operands. BK=64 stored as 2 half-tiles
// of [*][32] each (keeps the conflict-free 64B row stride + legal gl_lds).
// MODE 0: merged QKV projection. A=x(h,l) [SQ,DD], B=Wqkv^T(h,l) [3072,DD].
//         128x128, BK=32, grid (24,32). bn<16 (Q,K): split3 + hi/lo split-store.
//         bn>=16 (V): hi-only + transposed f16 store.
// MODE 1: QK^T. split3, 128x128, BK=64, causal block skip, f32*scale store.
//         grid (32,32), 528 active blocks (~2/CU -> 64KB LDS costs nothing).
// MODE 2: PV. A=P f16 [SQ,SQ], B=Vt f16 [DD,SQ], hi-only, 64x128, BK=64,
//         kend=((bm>>1)+1)*128 (P zero-filled to that boundary). grid (8,64).
template<int MODE>
__global__ __launch_bounds__(256)
void gemm_k(const f16* __restrict__ Ah, const f16* __restrict__ Al,
            const f16* __restrict__ Bh, const f16* __restrict__ Bl,
            float* __restrict__ Cf,
            f16* __restrict__ Qh, f16* __restrict__ Ql,
            f16* __restrict__ Kh, f16* __restrict__ Kl,
            f16* __restrict__ Vt, float scale)
{
    constexpr int TM = (MODE == 2) ? 64 : 128;
    constexpr int NI = (MODE == 2) ? 2 : 4;       // 16-col frags per wave
    constexpr int H  = (MODE == 0) ? 1 : 2;       // BK/32 half-tiles
    constexpr int AH = TM * 32;                   // f16 elems per A half-tile
    constexpr int BH = 128 * 32;
    constexpr int SMSZ = (MODE == 2) ? H * (AH + BH) : 2 * H * (AH + BH);

    const int bn = blockIdx.x, bm = blockIdx.y;
    if (MODE == 1 && bn > bm) return;
    const int m0 = bm * TM;
    const int n0 = bn << 7;
    const int lda = (MODE == 2) ? SQ : DD;
    const int ldb = (MODE == 2) ? SQ : DD;
    const int kend = (MODE == 2) ? (((bm >> 1) + 1) << 7) : DD;
    const bool dolo = (MODE == 1) || (MODE == 0 && bn < 16);

    __shared__ f16 sm[SMSZ];
    f16* smA  = sm;
    f16* smB  = sm + H * AH;
    f16* smAl = sm + H * (AH + BH);
    f16* smBl = smAl + H * AH;

    const int tid = threadIdx.x;
    const int w = tid >> 6, lane = tid & 63;
    const int wr = (MODE == 2) ? 0 : ((w >> 1) << 6);
    const int wc = (MODE == 2) ? (w << 5) : ((w & 1) << 6);
    const int fcol = lane & 15, quad = lane >> 4;

    f32x4 acc[4][NI];
#pragma unroll
    for (int i = 0; i < 4; ++i)
#pragma unroll
        for (int j = 0; j < NI; ++j) acc[i][j] = (f32x4){0.f, 0.f, 0.f, 0.f};

    const f16* Ab = Ah + (size_t)m0 * lda;
    const f16* Bb = Bh + (size_t)n0 * ldb;
    const f16* Abl = dolo ? Al + (size_t)m0 * lda : nullptr;
    const f16* Bbl = dolo ? Bl + (size_t)n0 * ldb : nullptr;

    for (int k0 = 0; k0 < kend; k0 += 32 * H) {
        __syncthreads();                          // prev iter's ds_reads done
#pragma unroll
        for (int h = 0; h < H; ++h) {
            stage<TM / 4>(Ab + k0 + 32 * h, lda, smA + h * AH, w, lane);
            stage<32>(Bb + k0 + 32 * h, ldb, smB + h * BH, w, lane);
            if (dolo) {
                stage<TM / 4>(Abl + k0 + 32 * h, lda, smAl + h * AH, w, lane);
                stage<32>(Bbl + k0 + 32 * h, ldb, smBl + h * BH, w, lane);
            }
        }
        __syncthreads();                          // vmcnt drained -> LDS valid

#pragma unroll
        for (int h = 0; h < H; ++h) {
            f16x8 bh[NI], bl[NI];
#pragma unroll
            for (int in = 0; in < NI; ++in) {
                const int off = ((wc + (in << 4) + fcol) << 5) + (quad << 3);
                bh[in] = *(const f16x8*)&smB[h * BH + off];
                if (dolo) bl[in] = *(const f16x8*)&smBl[h * BH + off];
            }
#pragma unroll
            for (int im = 0; im < 4; ++im) {
                const int off = ((wr + (im << 4) + fcol) << 5) + (quad << 3);
                f16x8 ah = *(const f16x8*)&smA[h * AH + off];
                f16x8 al;
                if (dolo) al = *(const f16x8*)&smAl[h * AH + off];
#pragma unroll
                for (int in = 0; in < NI; ++in) {
                    if (dolo) {
                        acc[im][in] = __builtin_amdgcn_mfma_f32_16x16x32_f16(ah, bl[in], acc[im][in], 0, 0, 0);
                        acc[im][in] = __builtin_amdgcn_mfma_f32_16x16x32_f16(al, bh[in], acc[im][in], 0, 0, 0);
                    }
                    acc[im][in] = __builtin_amdgcn_mfma_f32_16x16x32_f16(ah, bh[in], acc[im][in], 0, 0, 0);
                }
            }
        }
    }

    // C/D layout: col = lane&15, row = quad*4 + r  [m89-verified]
#pragma unroll
    for (int im = 0; im < 4; ++im) {
#pragma unroll
        for (int in = 0; in < NI; ++in) {
            if (MODE == 0) {
                const int region = bn >> 3;                       // 0=Q 1=K 2=V
                const int colL = ((bn & 7) << 7) + wc + (in << 4) + fcol;
                if (region == 2) {
                    const int tc = m0 + wr + (im << 4) + (quad << 2);
                    f16x4 o;
#pragma unroll
                    for (int r = 0; r < 4; ++r) o[r] = (f16)acc[im][in][r];
                    *(f16x4*)&Vt[(size_t)colL * SQ + tc] = o;
                } else {
                    f16* Hh = region ? Kh : Qh;
                    f16* Hl = region ? Kl : Ql;
#pragma unroll
                    for (int r = 0; r < 4; ++r) {
                        const int row = m0 + wr + (im << 4) + (quad << 2) + r;
                        const float v = acc[im][in][r];
                        const f16 h = (f16)v;
                        Hh[(size_t)row * DD + colL] = h;
                        Hl[(size_t)row * DD + colL] = (f16)(v - (float)h);
                    }
                }
            } else {
                const int ldc = (MODE == 1) ? SQ : DD;
#pragma unroll
                for (int r = 0; r < 4; ++r) {
                    const int row = m0 + wr + (im << 4) + (quad << 2) + r;
                    const int col = n0 + wc + (in << 4) + fcol;
                    Cf[(size_t)row * ldc + col] = acc[im][in][r] * scale;
                }
            }
        }
    }
}

// x (fp32) -> hi/lo f16 split, elementwise
__global__ __launch_bounds__(256)
void split_f32(const float* __restrict__ x, f16* __restrict__ h, f16* __restrict__ l, int n)
{
    const int i = (blockIdx.x * 256 + threadIdx.x) * 4;
    if (i >= n) return;
    const float4 v = *(const float4*)(x + i);
    const f16 h0 = (f16)v.x, h1 = (f16)v.y, h2 = (f16)v.z, h3 = (f16)v.w;
    f16x4 hv = {h0, h1, h2, h3};
    f16x4 lv = {(f16)(v.x - (float)h0), (f16)(v.y - (float)h1),
                (f16)(v.z - (float)h2), (f16)(v.w - (float)h3)};
    *(f16x4*)(h + i) = hv;
    *(f16x4*)(l + i) = lv;
}

// W [K,N] f32 row-major -> Th,Tl [N,K] f16 (transposed hi/lo split).
// z-batched over the 3 weight matrices (written into one [3072,1024] buffer).
__global__ __launch_bounds__(256)
void transpose_split3(const float* __restrict__ W0, const float* __restrict__ W1,
                      const float* __restrict__ W2,
                      f16* __restrict__ Th0, f16* __restrict__ Tl0,
                      int K, int N)
{
    const float* W = (blockIdx.z == 0) ? W0 : (blockIdx.z == 1) ? W1 : W2;
    f16* Th = Th0 + (size_t)blockIdx.z * K * N;
    f16* Tl = Tl0 + (size_t)blockIdx.z * K * N;

    __shared__ float t[64][65];
    const int n0 = blockIdx.x << 6, k0 = blockIdx.y << 6;
    const int tx = threadIdx.x & 63, ty = threadIdx.x >> 6;
    for (int r = ty; r < 64; r += 4) t[r][tx] = W[(size_t)(k0 + r) * N + n0 + tx];
    __syncthreads();
    for (int r = ty; r < 64; r += 4) {
        const float v = t[tx][r];
        const f16 h = (f16)v;
        Th[(size_t)(n0 + r) * K + k0 + tx] = h;
        Tl[(size_t)(n0 + r) * K + k0 + tx] = (f16)(v - (float)h);
    }
}

// Row-wise causal softmax: reads f32 logits once, stashes exp in LDS, writes
// f16 P scaled; zero-fills to the row's 128-tile boundary for PV staging.
__global__ __launch_bounds__(256)
void softmax_causal(const float* __restrict__ A, f16* __restrict__ P)
{
    const int i = blockIdx.x;
    const float* row = A + (size_t)i * SQ;
    f16* prow = P + (size_t)i * SQ;
    const int n = i + 1;
    const int tid = threadIdx.x, w = tid >> 6, lane = tid & 63;
    __shared__ float redM[4], redS[4];
    __shared__ float rowbuf[SQ];                 // 16 KB exp stash

    float m = -INFINITY;
    for (int j = tid; j < n; j += 256) m = fmaxf(m, row[j]);
    m = waveMax(m);
    if (lane == 0) redM[w] = m;
    __syncthreads();
    const float mAll = fmaxf(fmaxf(redM[0], redM[1]), fmaxf(redM[2], redM[3]));

    float s = 0.f;
    for (int j = tid; j < n; j += 256) {
        const float e = __expf(row[j] - mAll);
        rowbuf[j] = e;
        s += e;
    }
    s = waveSum(s);
    if (lane == 0) redS[w] = s;
    __syncthreads();
    const float inv = 1.0f / (redS[0] + redS[1] + redS[2] + redS[3]);

    for (int j = tid; j < n; j += 256) prow[j] = (f16)(rowbuf[j] * inv);

    const int kmax = ((i >> 7) + 1) << 7;
    for (int j = n + tid; j < kmax; j += 256) prow[j] = (f16)0.f;
}

extern "C" void kernel_launch(void* const* d_in, const int* in_sizes, int n_in,
                              void* d_out, int out_size, void* d_ws, size_t ws_size,
                              hipStream_t stream)
{
    const float* x  = (const float*)d_in[0];
    const float* Wq = (const float*)d_in[1];
    const float* Wk = (const float*)d_in[2];
    const float* Wv = (const float*)d_in[3];
    float* out = (float*)d_out;

    // workspace carve (~164 MB)
    char* p = (char*)d_ws;
    auto take = [&](size_t bytes) { void* r = (void*)p; p += (bytes + 255) & ~(size_t)255; return r; };
    const size_t SD = (size_t)SQ * DD;          // 4M elems
    f16* xh  = (f16*)take(SD * 2);
    f16* xl  = (f16*)take(SD * 2);
    f16* Wth = (f16*)take((size_t)3 * DD * DD * 2);   // [3072][1024] = Wq^T|Wk^T|Wv^T
    f16* Wtl = (f16*)take((size_t)3 * DD * DD * 2);
    f16* Qh  = (f16*)take(SD * 2);
    f16* Ql  = (f16*)take(SD * 2);
    f16* Kh  = (f16*)take(SD * 2);
    f16* Kl  = (f16*)take(SD * 2);
    f16* Vt  = (f16*)take(SD * 2);              // [DD][SQ]
    float* attn = (float*)take((size_t)SQ * SQ * 4);
    f16* P   = (f16*)take((size_t)SQ * SQ * 2);

    const dim3 blk(256);

    split_f32<<<dim3(SD / 4 / 256), blk, 0, stream>>>(x, xh, xl, (int)SD);
    transpose_split3<<<dim3(DD / 64, DD / 64, 3), blk, 0, stream>>>(
        Wq, Wk, Wv, Wth, Wtl, DD, DD);

    // Merged QKV projection: 768 blocks, BK=32
    gemm_k<0><<<dim3(24, SQ / 128), blk, 0, stream>>>(
        xh, xl, Wth, Wtl, nullptr, Qh, Ql, Kh, Kl, Vt, 1.0f);

    // attn = Q @ K^T / 32 : 128x128 tiles, BK=64, 528 causal blocks
    gemm_k<1><<<dim3(SQ / 128, SQ / 128), blk, 0, stream>>>(
        Qh, Ql, Kh, Kl, attn, nullptr, nullptr, nullptr, nullptr, nullptr, 0.03125f);

    softmax_causal<<<dim3(SQ), blk, 0, stream>>>(attn, P);

    // out = P @ V : 64x128 tiles, BK=64, 512 blocks, k-limited
    gemm_k<2><<<dim3(DD / 128, SQ / 64), blk, 0, stream>>>(
        P, nullptr, Vt, nullptr, out, nullptr, nullptr, nullptr, nullptr, nullptr, 1.0f);
}

// Round 6
// 300.394 us; speedup vs baseline: 4.0772x; 1.0092x over previous
//
#include <hip/hip_runtime.h>
#include <math.h>

#define SQ 4096
#define DD 1024
#define TRI 528          // causal 128x128 tiles in a 32x32 grid

typedef _Float16 f16;
typedef f16 f16x8 __attribute__((ext_vector_type(8)));
typedef f16 f16x4 __attribute__((ext_vector_type(4)));
typedef float f32x4 __attribute__((ext_vector_type(4)));

__device__ __forceinline__ float waveMax(float v) {
#pragma unroll
    for (int o = 32; o > 0; o >>= 1) v = fmaxf(v, __shfl_down(v, o, 64));
    return v;
}
__device__ __forceinline__ float waveSum(float v) {
#pragma unroll
    for (int o = 32; o > 0; o >>= 1) v += __shfl_down(v, o, 64);
    return v;
}

__device__ __forceinline__ void gl_lds16(const f16* g, f16* l) {
    __builtin_amdgcn_global_load_lds(
        (const __attribute__((address_space(1))) void*)g,
        (__attribute__((address_space(3))) void*)l, 16, 0, 0);
}

// Wave w stages NRW rows of a [*,32] f16 tile into LDS row-major [rows][32].
// gl_lds dest = wave-uniform base + lane*16B: lane L -> row w*NRW + L/4, chunk L%4.
template<int NRW>
__device__ __forceinline__ void stage(const f16* src, int ldk, f16* lds, int w, int lane) {
    const int r0 = w * NRW + (lane >> 2);
    const f16* g = src + (size_t)r0 * ldk + ((lane & 3) << 3);
    f16* l = lds + w * NRW * 32;
    gl_lds16(g, l);
    if (NRW == 32) gl_lds16(g + (size_t)ldk * 16, l + 16 * 32);
}

// Unified TN GEMM over K-contiguous f16 operands.
// MODE 0: merged QKV projection. A=x(h,l) [SQ,DD], B=Wqkv^T(h,l) [3072,DD].
//         128x128, BK=32, grid (24,32). bn<16 (Q,K): split3 + hi/lo split-store.
//         bn>=16 (V): hi-only + transposed f16 store.
// MODE 1: QK^T split-K=2. split3, 128x128, BK=32, grid = 1-D 1056:
//         id = (tri<<1)|half; tri decodes to causal (bm,bn); each block does
//         K in [half*512, half*512+512). Partial f32 stored packed-triangular
//         (slot tri, 128x128 row-major) at Cf + half*TRI*16384, *scale.
//         1056 blocks @32KB LDS -> ~4.1 resident/CU (the residency lever).
// MODE 2: PV. A=P f16 packed-triangular, B=Vt f16 [DD,SQ], hi-only, 64x128,
//         BK=64, kend=(bmT+1)*128. grid (8,64) with bm REVERSED (longest first).
template<int MODE>
__global__ __launch_bounds__(256)
void gemm_k(const f16* __restrict__ Ah, const f16* __restrict__ Al,
            const f16* __restrict__ Bh, const f16* __restrict__ Bl,
            float* __restrict__ Cf,
            f16* __restrict__ Qh, f16* __restrict__ Ql,
            f16* __restrict__ Kh, f16* __restrict__ Kl,
            f16* __restrict__ Vt, float scale)
{
    constexpr int TM = (MODE == 2) ? 64 : 128;
    constexpr int NI = (MODE == 2) ? 2 : 4;       // 16-col frags per wave
    constexpr int H  = (MODE == 2) ? 2 : 1;       // BK/32 half-tiles
    constexpr int AH = TM * 32;                   // f16 elems per A half-tile
    constexpr int BH = 128 * 32;
    constexpr int SMSZ = (MODE == 2) ? H * (AH + BH) : 2 * H * (AH + BH);

    int bm, bn, tri = 0, half = 0;
    if (MODE == 1) {
        const int id = blockIdx.x;
        half = id & 1;
        tri = id >> 1;
        bm = (int)((sqrtf(8.f * (float)tri + 1.f) - 1.f) * 0.5f);
        while ((bm + 1) * (bm + 2) / 2 <= tri) ++bm;
        while (bm * (bm + 1) / 2 > tri) --bm;
        bn = tri - bm * (bm + 1) / 2;
    } else if (MODE == 2) {
        bn = blockIdx.x;
        bm = (int)gridDim.y - 1 - (int)blockIdx.y;   // longest blocks first
    } else {
        bn = blockIdx.x; bm = blockIdx.y;
    }

    const int m0 = bm * TM;
    const int n0 = bn << 7;
    const int lda = (MODE == 2) ? 128 : DD;       // MODE2 A = packed tile rows
    const int ldb = (MODE == 2) ? SQ : DD;
    const int kst = (MODE == 1) ? (half << 9) : 0;
    const int kend = (MODE == 1) ? (kst + 512)
                   : (MODE == 2) ? (((bm >> 1) + 1) << 7) : DD;
    const bool dolo = (MODE == 1) || (MODE == 0 && bn < 16);

    __shared__ f16 sm[SMSZ];
    f16* smA  = sm;
    f16* smB  = sm + H * AH;
    f16* smAl = sm + H * (AH + BH);
    f16* smBl = smAl + H * AH;

    const int tid = threadIdx.x;
    const int w = tid >> 6, lane = tid & 63;
    const int wr = (MODE == 2) ? 0 : ((w >> 1) << 6);
    const int wc = (MODE == 2) ? (w << 5) : ((w & 1) << 6);
    const int fcol = lane & 15, quad = lane >> 4;

    f32x4 acc[4][NI];
#pragma unroll
    for (int i = 0; i < 4; ++i)
#pragma unroll
        for (int j = 0; j < NI; ++j) acc[i][j] = (f32x4){0.f, 0.f, 0.f, 0.f};

    // A base: MODE2 reads packed-triangular P (tile row bmT fixed, tile col = k>>7)
    const int bmT = (MODE == 2) ? (bm >> 1) : 0;
    const size_t triRow = (MODE == 2) ? (size_t)(bmT * (bmT + 1) / 2) : 0;
    const f16* Ab  = Ah + (size_t)m0 * ((MODE == 2) ? 0 : DD);
    const f16* Bb  = Bh + (size_t)n0 * ldb;
    const f16* Abl = dolo ? Al + (size_t)m0 * DD : nullptr;
    const f16* Bbl = dolo ? Bl + (size_t)n0 * ldb : nullptr;

    for (int k0 = kst; k0 < kend; k0 += 32 * H) {
        __syncthreads();                          // prev iter's ds_reads done
#pragma unroll
        for (int h = 0; h < H; ++h) {
            const int kk = k0 + 32 * h;
            const f16* as;
            if (MODE == 2) {
                as = Ah + ((triRow + (size_t)(kk >> 7)) << 14)
                        + ((size_t)(m0 & 127) << 7) + (kk & 127);
            } else {
                as = Ab + kk;
            }
            stage<TM / 4>(as, lda, smA + h * AH, w, lane);
            stage<32>(Bb + kk, ldb, smB + h * BH, w, lane);
            if (dolo) {
                stage<TM / 4>(Abl + kk, DD, smAl + h * AH, w, lane);
                stage<32>(Bbl + kk, ldb, smBl + h * BH, w, lane);
            }
        }
        __syncthreads();                          // vmcnt drained -> LDS valid

#pragma unroll
        for (int h = 0; h < H; ++h) {
            f16x8 bh[NI], bl[NI];
#pragma unroll
            for (int in = 0; in < NI; ++in) {
                const int off = ((wc + (in << 4) + fcol) << 5) + (quad << 3);
                bh[in] = *(const f16x8*)&smB[h * BH + off];
                if (dolo) bl[in] = *(const f16x8*)&smBl[h * BH + off];
            }
#pragma unroll
            for (int im = 0; im < 4; ++im) {
                const int off = ((wr + (im << 4) + fcol) << 5) + (quad << 3);
                f16x8 ah = *(const f16x8*)&smA[h * AH + off];
                f16x8 al;
                if (dolo) al = *(const f16x8*)&smAl[h * AH + off];
#pragma unroll
                for (int in = 0; in < NI; ++in) {
                    if (dolo) {
                        acc[im][in] = __builtin_amdgcn_mfma_f32_16x16x32_f16(ah, bl[in], acc[im][in], 0, 0, 0);
                        acc[im][in] = __builtin_amdgcn_mfma_f32_16x16x32_f16(al, bh[in], acc[im][in], 0, 0, 0);
                    }
                    acc[im][in] = __builtin_amdgcn_mfma_f32_16x16x32_f16(ah, bh[in], acc[im][in], 0, 0, 0);
                }
            }
        }
    }

    // C/D layout: col = lane&15, row = quad*4 + r  [m89-verified]
#pragma unroll
    for (int im = 0; im < 4; ++im) {
#pragma unroll
        for (int in = 0; in < NI; ++in) {
            if (MODE == 0) {
                const int region = bn >> 3;                       // 0=Q 1=K 2=V
                const int colL = ((bn & 7) << 7) + wc + (in << 4) + fcol;
                if (region == 2) {
                    const int tc = m0 + wr + (im << 4) + (quad << 2);
                    f16x4 o;
#pragma unroll
                    for (int r = 0; r < 4; ++r) o[r] = (f16)acc[im][in][r];
                    *(f16x4*)&Vt[(size_t)colL * SQ + tc] = o;
                } else {
                    f16* Hh = region ? Kh : Qh;
                    f16* Hl = region ? Kl : Ql;
#pragma unroll
                    for (int r = 0; r < 4; ++r) {
                        const int row = m0 + wr + (im << 4) + (quad << 2) + r;
                        const float v = acc[im][in][r];
                        const f16 h = (f16)v;
                        Hh[(size_t)row * DD + colL] = h;
                        Hl[(size_t)row * DD + colL] = (f16)(v - (float)h);
                    }
                }
            } else if (MODE == 1) {
                float* Cp = Cf + (((size_t)half * TRI + tri) << 14);
#pragma unroll
                for (int r = 0; r < 4; ++r) {
                    const int rl = wr + (im << 4) + (quad << 2) + r;   // local row
                    const int cl = wc + (in << 4) + fcol;              // local col
                    Cp[(rl << 7) + cl] = acc[im][in][r] * scale;
                }
            } else {
#pragma unroll
                for (int r = 0; r < 4; ++r) {
                    const int row = m0 + wr + (im << 4) + (quad << 2) + r;
                    const int col = n0 + wc + (in << 4) + fcol;
                    Cf[(size_t)row * DD + col] = acc[im][in][r];
                }
            }
        }
    }
}

// x (fp32) -> hi/lo f16 split, elementwise
__global__ __launch_bounds__(256)
void split_f32(const float* __restrict__ x, f16* __restrict__ h, f16* __restrict__ l, int n)
{
    const int i = (blockIdx.x * 256 + threadIdx.x) * 4;
    if (i >= n) return;
    const float4 v = *(const float4*)(x + i);
    const f16 h0 = (f16)v.x, h1 = (f16)v.y, h2 = (f16)v.z, h3 = (f16)v.w;
    f16x4 hv = {h0, h1, h2, h3};
    f16x4 lv = {(f16)(v.x - (float)h0), (f16)(v.y - (float)h1),
                (f16)(v.z - (float)h2), (f16)(v.w - (float)h3)};
    *(f16x4*)(h + i) = hv;
    *(f16x4*)(l + i) = lv;
}

// W [K,N] f32 row-major -> Th,Tl [N,K] f16 (transposed hi/lo split).
// z-batched over the 3 weight matrices (into one [3072,1024] buffer).
__global__ __launch_bounds__(256)
void transpose_split3(const float* __restrict__ W0, const float* __restrict__ W1,
                      const float* __restrict__ W2,
                      f16* __restrict__ Th0, f16* __restrict__ Tl0,
                      int K, int N)
{
    const float* W = (blockIdx.z == 0) ? W0 : (blockIdx.z == 1) ? W1 : W2;
    f16* Th = Th0 + (size_t)blockIdx.z * K * N;
    f16* Tl = Tl0 + (size_t)blockIdx.z * K * N;

    __shared__ float t[64][65];
    const int n0 = blockIdx.x << 6, k0 = blockIdx.y << 6;
    const int tx = threadIdx.x & 63, ty = threadIdx.x >> 6;
    for (int r = ty; r < 64; r += 4) t[r][tx] = W[(size_t)(k0 + r) * N + n0 + tx];
    __syncthreads();
    for (int r = ty; r < 64; r += 4) {
        const float v = t[tx][r];
        const f16 h = (f16)v;
        Th[(size_t)(n0 + r) * K + k0 + tx] = h;
        Tl[(size_t)(n0 + r) * K + k0 + tx] = (f16)(v - (float)h);
    }
}

// Row-wise causal softmax over packed-triangular split-K partials.
// logit[i][j] = A0[slot] + A1[slot]; writes f16 P packed-triangular, zero-fills
// to the row's 128-tile boundary for PV staging.
__global__ __launch_bounds__(256)
void softmax_causal(const float* __restrict__ A0, f16* __restrict__ P)
{
    const int i = blockIdx.x;
    const int n = i + 1;
    const int tid = threadIdx.x, w = tid >> 6, lane = tid & 63;
    __shared__ float redM[4], redS[4];
    __shared__ float rowbuf[SQ];                 // 16 KB exp stash

    const int bmI = i >> 7;
    const size_t base = ((size_t)(bmI * (bmI + 1) / 2) << 14) + ((size_t)(i & 127) << 7);
    const float* A1 = A0 + ((size_t)TRI << 14);

    float m = -INFINITY;
    for (int j = tid; j < n; j += 256) {
        const size_t a = base + ((size_t)(j >> 7) << 14) + (j & 127);
        const float v = A0[a] + A1[a];
        rowbuf[j] = v;
        m = fmaxf(m, v);
    }
    m = waveMax(m);
    if (lane == 0) redM[w] = m;
    __syncthreads();
    const float mAll = fmaxf(fmaxf(redM[0], redM[1]), fmaxf(redM[2], redM[3]));

    float s = 0.f;
    for (int j = tid; j < n; j += 256) {
        const float e = __expf(rowbuf[j] - mAll);
        rowbuf[j] = e;
        s += e;
    }
    s = waveSum(s);
    if (lane == 0) redS[w] = s;
    __syncthreads();
    const float inv = 1.0f / (redS[0] + redS[1] + redS[2] + redS[3]);

    const int kmax = (bmI + 1) << 7;             // P zero-fill boundary
    for (int j = tid; j < kmax; j += 256) {
        const size_t a = base + ((size_t)(j >> 7) << 14) + (j & 127);
        P[a] = (j < n) ? (f16)(rowbuf[j] * inv) : (f16)0.f;
    }
}

extern "C" void kernel_launch(void* const* d_in, const int* in_sizes, int n_in,
                              void* d_out, int out_size, void* d_ws, size_t ws_size,
                              hipStream_t stream)
{
    const float* x  = (const float*)d_in[0];
    const float* Wq = (const float*)d_in[1];
    const float* Wk = (const float*)d_in[2];
    const float* Wv = (const float*)d_in[3];
    float* out = (float*)d_out;

    // workspace carve (~155 MB)
    char* p = (char*)d_ws;
    auto take = [&](size_t bytes) { void* r = (void*)p; p += (bytes + 255) & ~(size_t)255; return r; };
    const size_t SD = (size_t)SQ * DD;          // 4M elems
    f16* xh  = (f16*)take(SD * 2);
    f16* xl  = (f16*)take(SD * 2);
    f16* Wth = (f16*)take((size_t)3 * DD * DD * 2);   // [3072][1024] = Wq^T|Wk^T|Wv^T
    f16* Wtl = (f16*)take((size_t)3 * DD * DD * 2);
    f16* Qh  = (f16*)take(SD * 2);
    f16* Ql  = (f16*)take(SD * 2);
    f16* Kh  = (f16*)take(SD * 2);
    f16* Kl  = (f16*)take(SD * 2);
    f16* Vt  = (f16*)take(SD * 2);              // [DD][SQ]
    float* attn = (float*)take((size_t)2 * TRI * 16384 * 4);  // 2 split-K partials, packed
    f16* P   = (f16*)take((size_t)TRI * 16384 * 2);           // packed triangular

    const dim3 blk(256);

    split_f32<<<dim3(SD / 4 / 256), blk, 0, stream>>>(x, xh, xl, (int)SD);
    transpose_split3<<<dim3(DD / 64, DD / 64, 3), blk, 0, stream>>>(
        Wq, Wk, Wv, Wth, Wtl, DD, DD);

    // Merged QKV projection: 768 blocks, BK=32
    gemm_k<0><<<dim3(24, SQ / 128), blk, 0, stream>>>(
        xh, xl, Wth, Wtl, nullptr, Qh, Ql, Kh, Kl, Vt, 1.0f);

    // attn partials = Q @ K^T / 32 : split-K=2, 1056 blocks, 32KB LDS
    gemm_k<1><<<dim3(2 * TRI), blk, 0, stream>>>(
        Qh, Ql, Kh, Kl, attn, nullptr, nullptr, nullptr, nullptr, nullptr, 0.03125f);

    softmax_causal<<<dim3(SQ), blk, 0, stream>>>(attn, P);

    // out = P @ V : 64x128 tiles, BK=64, 512 blocks, longest-first
    gemm_k<2><<<dim3(DD / 128, SQ / 64), blk, 0, stream>>>(
        P, nullptr, Vt, nullptr, out, nullptr, nullptr, nullptr, nullptr, nullptr, 1.0f);
}